// Round 16
// baseline (333.767 us; speedup 1.0000x reference)
//
#include <hip/hip_runtime.h>

#define NEG_INF_F (-1.0e9f)

typedef _Float16 f16x8 __attribute__((ext_vector_type(8)));
typedef float f32x4 __attribute__((ext_vector_type(4)));
typedef float f32x16 __attribute__((ext_vector_type(16)));

__device__ inline unsigned short f16_of(float f) {
    _Float16 h = (_Float16)f;
    return __builtin_bit_cast(unsigned short, h);
}
__device__ inline float f32_of(unsigned short u) {
    return (float)__builtin_bit_cast(_Float16, u);
}

// async global->LDS, 16B per lane; LDS dest = wave-uniform base + lane*16
__device__ inline void gload16(const unsigned short* g, unsigned short* l) {
    __builtin_amdgcn_global_load_lds(
        (const __attribute__((address_space(1))) unsigned int*)g,
        (__attribute__((address_space(3))) unsigned int*)l, 16, 0, 0);
}

// [R][32]-f16 tile, chunk swizzle ^((r>>1)&3)
__device__ inline f16x8 frag32(const unsigned short* t, int r, int ch) {
    return *reinterpret_cast<const f16x8*>(&t[r * 32 + (ch ^ ((r >> 1) & 3)) * 8]);
}
// [R][64]-f16 tile, chunk swizzle ^(r&7)
__device__ inline f16x8 frag64(const unsigned short* t, int r, int ch) {
    return *reinterpret_cast<const f16x8*>(&t[r * 64 + (ch ^ (r & 7)) * 8]);
}

// Stage a 256x32 f16 tile: 2 gloads per wave.
__device__ inline void stage_256x32(const unsigned short* __restrict__ g0, int ldg, int k0,
                                    unsigned short* qbuf, int w, int lane) {
#pragma unroll
    for (int c = 0; c < 2; ++c) {
        const int r = c * 128 + w * 16 + (lane >> 2);
        const int co = ((lane & 3) ^ ((r >> 1) & 3)) * 8;
        gload16(g0 + (long long)r * ldg + k0 + co, qbuf + (c * 128 + w * 16) * 32);
    }
}
// Stage a 128x32 f16 tile: 1 gload per wave.
__device__ inline void stage_128x32(const unsigned short* __restrict__ g0, int ldg, int k0,
                                    unsigned short* qbuf, int w, int lane) {
    const int r = w * 16 + (lane >> 2);
    const int co = ((lane & 3) ^ ((r >> 1) & 3)) * 8;
    gload16(g0 + (long long)r * ldg + k0 + co, qbuf + (w * 16) * 32);
}

// ======== TERMS-2 GEMM (Mt only): C = (Ah+Al) * B^T.  128x256, BK=32 ========
__global__ __launch_bounds__(512, 2) void gemm2(
    const unsigned short* __restrict__ Ah_g, const unsigned short* __restrict__ Al_g,
    int lda,
    const unsigned short* __restrict__ Bh_g, int ldb,
    unsigned short* __restrict__ Ch, int ldc, int K)
{
    constexpr int BUF = 16384;
    const int tid = threadIdx.x;
    const int w = tid >> 6, lane = tid & 63;
    const int wr = w & 1, wc = w >> 1;
    const int lr = lane & 15, lg = lane >> 4;
    const int rowBase = blockIdx.x * 128;
    const int colBase = blockIdx.y * 256;

    __shared__ unsigned short smem[32768];

    const unsigned short* Ah0 = Ah_g + (long long)rowBase * lda;
    const unsigned short* Al0 = Al_g + (long long)rowBase * lda;
    const unsigned short* Bh0 = Bh_g + (long long)colBase * ldb;

    f32x4 acc[4][4] = {};
    const int NT = K / 32;

    stage_128x32(Ah0, lda, 0, smem, w, lane);
    stage_128x32(Al0, lda, 0, smem + 4096, w, lane);
    stage_256x32(Bh0, ldb, 0, smem + 8192, w, lane);
    __syncthreads();

    for (int kt = 0; kt < NT; ++kt) {
        const unsigned short* cbuf = smem + (kt & 1) * BUF;
        if (kt + 1 < NT) {
            unsigned short* nbuf = smem + ((kt + 1) & 1) * BUF;
            const int k1 = (kt + 1) * 32;
            stage_128x32(Ah0, lda, k1, nbuf, w, lane);
            stage_128x32(Al0, lda, k1, nbuf + 4096, w, lane);
            stage_256x32(Bh0, ldb, k1, nbuf + 8192, w, lane);
        }
        const unsigned short* tAh = cbuf;
        const unsigned short* tAl = cbuf + 4096;
        const unsigned short* tB  = cbuf + 8192;
        f16x8 ah[4], al[4], bh[4];
#pragma unroll
        for (int i = 0; i < 4; ++i) {
            const int r = wr * 64 + i * 16 + lr;
            ah[i] = frag32(tAh, r, lg);
            al[i] = frag32(tAl, r, lg);
        }
#pragma unroll
        for (int j = 0; j < 4; ++j)
            bh[j] = frag32(tB, wc * 64 + j * 16 + lr, lg);
#pragma unroll
        for (int i = 0; i < 4; ++i)
#pragma unroll
            for (int j = 0; j < 4; ++j) {
                f32x4 a = acc[i][j];
                a = __builtin_amdgcn_mfma_f32_16x16x32_f16(ah[i], bh[j], a, 0, 0, 0);
                a = __builtin_amdgcn_mfma_f32_16x16x32_f16(al[i], bh[j], a, 0, 0, 0);
                acc[i][j] = a;
            }
        __syncthreads();
    }

    __syncthreads();
    float* stg = reinterpret_cast<float*>(smem) + w * 2048;
    const int colg0 = colBase + wc * 64;
#pragma unroll
    for (int rnd = 0; rnd < 2; ++rnd) {
        const int rowg0 = rowBase + wr * 64 + rnd * 32;
#pragma unroll
        for (int ii = 0; ii < 2; ++ii)
#pragma unroll
            for (int j = 0; j < 4; ++j)
#pragma unroll
                for (int r2 = 0; r2 < 4; ++r2)
                    stg[(ii * 16 + lg * 4 + r2) * 64 + j * 16 + lr] = acc[rnd * 2 + ii][j][r2];

#pragma unroll
        for (int t = 0; t < 8; ++t) {
            const int idx = t * 256 + lane * 4;
            const int r = idx >> 6, c = idx & 63;
            const float4 v = *reinterpret_cast<const float4*>(&stg[idx]);
            ushort4 h;
            h.x = f16_of(v.x); h.y = f16_of(v.y);
            h.z = f16_of(v.z); h.w = f16_of(v.w);
            *reinterpret_cast<ushort4*>(
                &Ch[(long long)(rowg0 + r) * ldc + colg0 + c]) = h;
        }
    }
}

// ======== TERMS-1 GEMM: 256x256, BK=64, 2-barrier loop, 32x32x16 MFMA =======
__device__ inline void stage_ktile1(
    const unsigned short* __restrict__ Ah0, int lda,
    const unsigned short* __restrict__ Bh0, int ldb,
    int k0, unsigned short* buf, int w, int lane)
{
#pragma unroll
    for (int c = 0; c < 4; ++c) {
        const int r = c * 64 + w * 8 + (lane >> 3);
        const int co = ((lane & 7) ^ (r & 7)) * 8;
        const int lb = (c * 64 + w * 8) * 64;
        gload16(Ah0 + (long long)r * lda + k0 + co, buf + lb);
        gload16(Bh0 + (long long)r * ldb + k0 + co, buf + 16384 + lb);
    }
}

// 8 waves (2 row x 4 col), wave tile 128x64 = 4x2 frags of 32x32.
// A/B fragment: row = base + (lane&31), k-chunk = ks*2 + (lane>>5).
// C/D layout: col = lane&31, row = (reg&3) + 8*(reg>>2) + 4*(lane>>5).
// OMODE: 0 = f32 C (+ optional NEG_INF*mask[col]);
//        4 = fused GV: cols<1024 -> f16 G (Ch, ldc); cols>=1024 -> f16 V^T
//            store Ch2[b2][col-1024][s]  (rows are [B*S], b2 = row>>11).
template <int OMODE>
__global__ __launch_bounds__(512, 2) void mfma_gemm1(
    const unsigned short* __restrict__ Ah_g, long long strideA, int lda,
    const unsigned short* __restrict__ Bh_g, long long strideB, int ldb,
    float* __restrict__ Cf, unsigned short* __restrict__ Ch, unsigned short* __restrict__ Ch2,
    long long strideC, int ldc, int K,
    const int* __restrict__ mask, long long strideMask)
{
    const int b = blockIdx.z;
    const int tid = threadIdx.x;
    const int w = tid >> 6, lane = tid & 63;
    const int wr = w >> 2, wc = w & 3;
    const int ln31 = lane & 31, lhi = lane >> 5;
    const int rowBase = blockIdx.x * 256;
    const int colBase = blockIdx.y * 256;

    __shared__ unsigned short smem[65536];  // 128 KB: 2 x 64KB

    const unsigned short* Ah0 = Ah_g + (long long)b * strideA + (long long)rowBase * lda;
    const unsigned short* Bh0 = Bh_g + (long long)b * strideB + (long long)colBase * ldb;

    f32x16 acc[4][2] = {};
    const int NT = K / 64;

    stage_ktile1(Ah0, lda, Bh0, ldb, 0, smem, w, lane);
    __syncthreads();

    for (int kt = 0; kt < NT; ++kt) {
        const unsigned short* cbuf = smem + (kt & 1) * 32768;
        if (kt + 1 < NT)
            stage_ktile1(Ah0, lda, Bh0, ldb, (kt + 1) * 64,
                         smem + ((kt + 1) & 1) * 32768, w, lane);

        const unsigned short* tA = cbuf;
        const unsigned short* tB = cbuf + 16384;
#pragma unroll
        for (int ks = 0; ks < 4; ++ks) {
            f16x8 bfr[2];
#pragma unroll
            for (int j = 0; j < 2; ++j)
                bfr[j] = frag64(tB, wc * 64 + j * 32 + ln31, ks * 2 + lhi);
#pragma unroll
            for (int fi = 0; fi < 4; ++fi) {
                const f16x8 afr = frag64(tA, wr * 128 + fi * 32 + ln31, ks * 2 + lhi);
#pragma unroll
                for (int j = 0; j < 2; ++j)
                    acc[fi][j] = __builtin_amdgcn_mfma_f32_32x32x16_f16(
                        afr, bfr[j], acc[fi][j], 0, 0, 0);
            }
        }
        __syncthreads();
    }

    // ---- epilogue: per-wave private LDS bounce (8KB each), 4 rounds 32x64 ----
    __syncthreads();
    float* stg = reinterpret_cast<float*>(smem) + w * 2048;
    const int colg0 = colBase + wc * 64;
#pragma unroll
    for (int rnd = 0; rnd < 4; ++rnd) {
        const int rowg0 = rowBase + wr * 128 + rnd * 32;
#pragma unroll
        for (int fj = 0; fj < 2; ++fj)
#pragma unroll
            for (int reg = 0; reg < 16; ++reg) {
                const int rif = (reg & 3) + 8 * (reg >> 2) + 4 * lhi;
                stg[rif * 64 + fj * 32 + ln31] = acc[rnd][fj][reg];
            }

        if constexpr (OMODE == 0) {
#pragma unroll
            for (int t = 0; t < 8; ++t) {
                const int idx = t * 256 + lane * 4;
                const int r = idx >> 6, c = idx & 63;
                float4 v = *reinterpret_cast<const float4*>(&stg[idx]);
                const int colg = colg0 + c;
                if (mask != nullptr) {
                    const int4 mv = *reinterpret_cast<const int4*>(
                        &mask[(long long)b * strideMask + colg]);
                    v.x += NEG_INF_F * (float)mv.x;
                    v.y += NEG_INF_F * (float)mv.y;
                    v.z += NEG_INF_F * (float)mv.z;
                    v.w += NEG_INF_F * (float)mv.w;
                }
                *reinterpret_cast<float4*>(
                    &Cf[(long long)b * strideC + (long long)(rowg0 + r) * ldc + colg]) = v;
            }
        } else {  // OMODE == 4: fused G | V^T
            if (colBase < 1024) {
#pragma unroll
                for (int t = 0; t < 8; ++t) {
                    const int idx = t * 256 + lane * 4;
                    const int r = idx >> 6, c = idx & 63;
                    const float4 v = *reinterpret_cast<const float4*>(&stg[idx]);
                    ushort4 h;
                    h.x = f16_of(v.x); h.y = f16_of(v.y);
                    h.z = f16_of(v.z); h.w = f16_of(v.w);
                    *reinterpret_cast<ushort4*>(
                        &Ch[(long long)(rowg0 + r) * ldc + colg0 + c]) = h;
                }
            } else {
                const int b2 = rowg0 >> 11;
                const int s0 = rowg0 & 2047;
                const int vcol = colg0 - 1024 + lane;
                alignas(16) unsigned short u[32];
#pragma unroll
                for (int rr = 0; rr < 32; ++rr) u[rr] = f16_of(stg[rr * 64 + lane]);
                unsigned short* vp = Ch2 + (long long)b2 * (1024LL * 2048)
                                   + (long long)vcol * 2048 + s0;
#pragma unroll
                for (int q = 0; q < 4; ++q)
                    *reinterpret_cast<uint4*>(vp + q * 8) =
                        *reinterpret_cast<const uint4*>(&u[q * 8]);
            }
        }
        __syncthreads();
    }
}

// ---------------- helpers ----------------
// f32 -> f16
__global__ __launch_bounds__(256) void cvt_kernel(
    const float* __restrict__ in, unsigned short* __restrict__ out, long long n)
{
    for (long long i = ((long long)blockIdx.x * 256 + threadIdx.x) * 4; i < n;
         i += (long long)gridDim.x * 256 * 4) {
        float4 v = *reinterpret_cast<const float4*>(&in[i]);
        ushort4 h;
        h.x = f16_of(v.x); h.y = f16_of(v.y); h.z = f16_of(v.z); h.w = f16_of(v.w);
        *reinterpret_cast<ushort4*>(&out[i]) = h;
    }
}

// Fused weight prep (z = 0: wq tsplit; z = 1: wk tsplit; z = 2: wv plain cvt).
// tsplit: f32 [N][N] -> TRANSPOSED hi/lo f16: hi[j][i] = split(in[i][j]).
__global__ __launch_bounds__(256) void wprep_kernel(
    const float* __restrict__ wq, const float* __restrict__ wk,
    const float* __restrict__ wv,
    unsigned short* __restrict__ wqTh, unsigned short* __restrict__ wqTl,
    unsigned short* __restrict__ wkTh, unsigned short* __restrict__ wkTl,
    unsigned short* __restrict__ wvh, int N)
{
    const int z = blockIdx.z;
    const int bi = blockIdx.x * 64;
    const int bj = blockIdx.y * 64;
    const int t = threadIdx.x;

    if (z == 2) {
        // plain cvt of a 64x64 tile of wv
        const int r = t >> 4;           // 0..15
        const int c4 = (t & 15) * 4;
#pragma unroll
        for (int rr = 0; rr < 4; ++rr) {
            const int row = bi + rr * 16 + r;
            float4 v = *reinterpret_cast<const float4*>(&wv[(long long)row * N + bj + c4]);
            ushort4 h;
            h.x = f16_of(v.x); h.y = f16_of(v.y);
            h.z = f16_of(v.z); h.w = f16_of(v.w);
            *reinterpret_cast<ushort4*>(&wvh[(long long)row * N + bj + c4]) = h;
        }
        return;
    }

    const float* in = (z == 0) ? wq : wk;
    unsigned short* hi = (z == 0) ? wqTh : wkTh;
    unsigned short* lo = (z == 0) ? wqTl : wkTl;

    __shared__ float tile[64][65];
    const int c4 = (t & 15) * 4;
    const int r0 = (t >> 4) * 4;
#pragma unroll
    for (int rr = 0; rr < 4; ++rr) {
        float4 v = *reinterpret_cast<const float4*>(
            &in[(long long)(bi + r0 + rr) * N + bj + c4]);
        tile[r0 + rr][c4 + 0] = v.x;
        tile[r0 + rr][c4 + 1] = v.y;
        tile[r0 + rr][c4 + 2] = v.z;
        tile[r0 + rr][c4 + 3] = v.w;
    }
    __syncthreads();
    const int oc  = t >> 2;
    const int or0 = (t & 3) * 16;
    alignas(16) unsigned short uh[16], ul[16];
#pragma unroll
    for (int e = 0; e < 16; ++e) {
        const float f = tile[or0 + e][oc];
        const unsigned short h = f16_of(f);
        uh[e] = h;
        ul[e] = f16_of(f - f32_of(h));
    }
    unsigned short* hp = hi + (long long)(bj + oc) * N + bi + or0;
    unsigned short* lp = lo + (long long)(bj + oc) * N + bi + or0;
    *reinterpret_cast<uint4*>(hp)     = *reinterpret_cast<const uint4*>(&uh[0]);
    *reinterpret_cast<uint4*>(hp + 8) = *reinterpret_cast<const uint4*>(&uh[8]);
    *reinterpret_cast<uint4*>(lp)     = *reinterpret_cast<const uint4*>(&ul[0]);
    *reinterpret_cast<uint4*>(lp + 8) = *reinterpret_cast<const uint4*>(&ul[8]);
}

// In-place f32 row softmax (rows=16384, cols=2048) + f16 copy for PV.
__global__ __launch_bounds__(256) void softmax_kernel(
    float* __restrict__ s, unsigned short* __restrict__ p)
{
    const long long row = blockIdx.x;
    float* sp = s + row * 2048;
    const int tid = threadIdx.x;

    float v[8];
    *reinterpret_cast<float4*>(&v[0]) = *reinterpret_cast<const float4*>(&sp[tid * 8]);
    *reinterpret_cast<float4*>(&v[4]) = *reinterpret_cast<const float4*>(&sp[tid * 8 + 4]);

    float m = v[0];
#pragma unroll
    for (int i = 1; i < 8; ++i) m = fmaxf(m, v[i]);
#pragma unroll
    for (int off = 1; off < 64; off <<= 1) m = fmaxf(m, __shfl_xor(m, off));

    __shared__ float redm[4];
    __shared__ float reds[4];
    if ((tid & 63) == 0) redm[tid >> 6] = m;
    __syncthreads();
    m = fmaxf(fmaxf(redm[0], redm[1]), fmaxf(redm[2], redm[3]));

    float sum = 0.f;
#pragma unroll
    for (int i = 0; i < 8; ++i) {
        v[i] = __expf(v[i] - m);
        sum += v[i];
    }
#pragma unroll
    for (int off = 1; off < 64; off <<= 1) sum += __shfl_xor(sum, off);
    if ((tid & 63) == 0) reds[tid >> 6] = sum;
    __syncthreads();
    sum = reds[0] + reds[1] + reds[2] + reds[3];

    const float inv = 1.0f / sum;
#pragma unroll
    for (int i = 0; i < 8; ++i) v[i] *= inv;

    *reinterpret_cast<float4*>(&sp[tid * 8])     = *reinterpret_cast<const float4*>(&v[0]);
    *reinterpret_cast<float4*>(&sp[tid * 8 + 4]) = *reinterpret_cast<const float4*>(&v[4]);

    ushort4 o0, o1;
    o0.x = f16_of(v[0]); o0.y = f16_of(v[1]); o0.z = f16_of(v[2]); o0.w = f16_of(v[3]);
    o1.x = f16_of(v[4]); o1.y = f16_of(v[5]); o1.z = f16_of(v[6]); o1.w = f16_of(v[7]);
    *reinterpret_cast<ushort4*>(&p[row * 2048 + tid * 8])     = o0;
    *reinterpret_cast<ushort4*>(&p[row * 2048 + tid * 8 + 4]) = o1;
}

extern "C" void kernel_launch(void* const* d_in, const int* in_sizes, int n_in,
                              void* d_out, int out_size, void* d_ws, size_t ws_size,
                              hipStream_t stream)
{
    (void)in_sizes; (void)n_in; (void)out_size; (void)ws_size;

    const int S = 2048, D = 1024;
    const long long BS  = 8LL * S;          // 16384
    const long long SD  = (long long)S * D;
    const long long SS  = (long long)S * S;
    const long long BSD = BS * D;
    const long long DD  = (long long)D * D;

    const float* x    = (const float*)d_in[0];
    const int*   mask = (const int*)d_in[1];
    const float* wq   = (const float*)d_in[2];
    const float* wk   = (const float*)d_in[3];
    const float* wv   = (const float*)d_in[4];

    float* out = (float*)d_out;             // [BS, D] f32 (final)
    float* s   = out + BSD;                 // [B, S, S] f32 (final)

    // ws layout (halves):
    //   G [16384][1024] | (free BSD)        <- later p [B][S][S] = 2*BSD halves
    //   Vt [B][D][S] | MtWv [2048][1024] (Mt rows 0-1023, wv rows 1024-2047)
    unsigned short* G    = (unsigned short*)d_ws;
    unsigned short* p    = G;               // overwrites G + free
    unsigned short* Vt   = G + 2 * BSD;
    unsigned short* MtWv = G + 3 * BSD;
    unsigned short* Mth  = MtWv;
    unsigned short* wvh  = MtWv + DD;

    // xh lives in d_out's out-region until PV overwrites it
    unsigned short* xh = (unsigned short*)out;
    // transposed weight splits live in d_out's s-region until scores overwrites it
    unsigned short* wqTh = (unsigned short*)s;   // [1024][1024] = wq^T hi
    unsigned short* wqTl = wqTh + DD;
    unsigned short* wkTh = wqTl + DD;
    unsigned short* wkTl = wkTh + DD;

    dim3 blk256(256), blk512(512);

    cvt_kernel<<<dim3(4096), blk256, 0, stream>>>(x, xh, BSD);
    wprep_kernel<<<dim3(16, 16, 3), blk256, 0, stream>>>(
        wq, wk, wv, wqTh, wqTl, wkTh, wkTl, wvh, D);

    // Mt[j][i] = sum_e wk[e][j]*wq[e][i]; A = (wkTh,wkTl) split, B = wqTh, f16 out
    gemm2<<<dim3(8, 4, 1), blk512, 0, stream>>>(
        wkTh, wkTl, D, wqTh, D, Mth, D, D);

    // Fused [G | V^T] = xh @ [Mt | wv]^T  (1-term, N=2048, mixed epilogue)
    mfma_gemm1<4><<<dim3(64, 8, 1), blk512, 0, stream>>>(
        xh, 0, D, MtWv, 0, D,
        nullptr, G, Vt, 0, D, D, nullptr, 0);

    // scores = G @ xh^T + NEG_INF*mask  (1-term, f32 out)
    mfma_gemm1<0><<<dim3(8, 8, 8), blk512, 0, stream>>>(
        G, SD, D, xh, SD, D,
        s, nullptr, nullptr, SS, S, D, mask, S);

    // softmax in place + f16 p for PV (p overwrites G)
    softmax_kernel<<<dim3(16384), blk256, 0, stream>>>(s, p);

    // out = p @ V = p @ (V^T)^T  (f32 out)
    mfma_gemm1<0><<<dim3(8, 4, 8), blk512, 0, stream>>>(
        p, SS, S, Vt, SD, S, out, nullptr, nullptr, SD, D, S, nullptr, 0);
}

// Round 17
// 310.319 us; speedup vs baseline: 1.0756x; 1.0756x over previous
//
#include <hip/hip_runtime.h>

#define NEG_INF_F (-1.0e9f)

typedef _Float16 f16x8 __attribute__((ext_vector_type(8)));
typedef float f32x4 __attribute__((ext_vector_type(4)));

__device__ inline unsigned short f16_of(float f) {
    _Float16 h = (_Float16)f;
    return __builtin_bit_cast(unsigned short, h);
}
__device__ inline float f32_of(unsigned short u) {
    return (float)__builtin_bit_cast(_Float16, u);
}

// async global->LDS, 16B per lane; LDS dest = wave-uniform base + lane*16
__device__ inline void gload16(const unsigned short* g, unsigned short* l) {
    __builtin_amdgcn_global_load_lds(
        (const __attribute__((address_space(1))) unsigned int*)g,
        (__attribute__((address_space(3))) unsigned int*)l, 16, 0, 0);
}

// [R][32]-f16 tile, chunk swizzle ^((r>>1)&3)
__device__ inline f16x8 frag32(const unsigned short* t, int r, int ch) {
    return *reinterpret_cast<const f16x8*>(&t[r * 32 + (ch ^ ((r >> 1) & 3)) * 8]);
}
// [R][64]-f16 tile, chunk swizzle ^(r&7)
__device__ inline f16x8 frag64(const unsigned short* t, int r, int ch) {
    return *reinterpret_cast<const f16x8*>(&t[r * 64 + (ch ^ (r & 7)) * 8]);
}

// Stage a 256x32 f16 tile: 2 gloads per wave.
__device__ inline void stage_256x32(const unsigned short* __restrict__ g0, int ldg, int k0,
                                    unsigned short* qbuf, int w, int lane) {
#pragma unroll
    for (int c = 0; c < 2; ++c) {
        const int r = c * 128 + w * 16 + (lane >> 2);
        const int co = ((lane & 3) ^ ((r >> 1) & 3)) * 8;
        gload16(g0 + (long long)r * ldg + k0 + co, qbuf + (c * 128 + w * 16) * 32);
    }
}
// Stage a 128x32 f16 tile: 1 gload per wave.
__device__ inline void stage_128x32(const unsigned short* __restrict__ g0, int ldg, int k0,
                                    unsigned short* qbuf, int w, int lane) {
    const int r = w * 16 + (lane >> 2);
    const int co = ((lane & 3) ^ ((r >> 1) & 3)) * 8;
    gload16(g0 + (long long)r * ldg + k0 + co, qbuf + (w * 16) * 32);
}

// ======== TERMS-2 GEMM (Mt only): C = (Ah+Al) * B^T.  128x256, BK=32 ========
__global__ __launch_bounds__(512, 2) void gemm2(
    const unsigned short* __restrict__ Ah_g, const unsigned short* __restrict__ Al_g,
    int lda,
    const unsigned short* __restrict__ Bh_g, int ldb,
    unsigned short* __restrict__ Ch, int ldc, int K)
{
    constexpr int BUF = 16384;
    const int tid = threadIdx.x;
    const int w = tid >> 6, lane = tid & 63;
    const int wr = w & 1, wc = w >> 1;
    const int lr = lane & 15, lg = lane >> 4;
    const int rowBase = blockIdx.x * 128;
    const int colBase = blockIdx.y * 256;

    __shared__ unsigned short smem[32768];

    const unsigned short* Ah0 = Ah_g + (long long)rowBase * lda;
    const unsigned short* Al0 = Al_g + (long long)rowBase * lda;
    const unsigned short* Bh0 = Bh_g + (long long)colBase * ldb;

    f32x4 acc[4][4] = {};
    const int NT = K / 32;

    stage_128x32(Ah0, lda, 0, smem, w, lane);
    stage_128x32(Al0, lda, 0, smem + 4096, w, lane);
    stage_256x32(Bh0, ldb, 0, smem + 8192, w, lane);
    __syncthreads();

    for (int kt = 0; kt < NT; ++kt) {
        const unsigned short* cbuf = smem + (kt & 1) * BUF;
        if (kt + 1 < NT) {
            unsigned short* nbuf = smem + ((kt + 1) & 1) * BUF;
            const int k1 = (kt + 1) * 32;
            stage_128x32(Ah0, lda, k1, nbuf, w, lane);
            stage_128x32(Al0, lda, k1, nbuf + 4096, w, lane);
            stage_256x32(Bh0, ldb, k1, nbuf + 8192, w, lane);
        }
        const unsigned short* tAh = cbuf;
        const unsigned short* tAl = cbuf + 4096;
        const unsigned short* tB  = cbuf + 8192;
        f16x8 ah[4], al[4], bh[4];
#pragma unroll
        for (int i = 0; i < 4; ++i) {
            const int r = wr * 64 + i * 16 + lr;
            ah[i] = frag32(tAh, r, lg);
            al[i] = frag32(tAl, r, lg);
        }
#pragma unroll
        for (int j = 0; j < 4; ++j)
            bh[j] = frag32(tB, wc * 64 + j * 16 + lr, lg);
#pragma unroll
        for (int i = 0; i < 4; ++i)
#pragma unroll
            for (int j = 0; j < 4; ++j) {
                f32x4 a = acc[i][j];
                a = __builtin_amdgcn_mfma_f32_16x16x32_f16(ah[i], bh[j], a, 0, 0, 0);
                a = __builtin_amdgcn_mfma_f32_16x16x32_f16(al[i], bh[j], a, 0, 0, 0);
                acc[i][j] = a;
            }
        __syncthreads();
    }

    __syncthreads();
    float* stg = reinterpret_cast<float*>(smem) + w * 2048;
    const int colg0 = colBase + wc * 64;
#pragma unroll
    for (int rnd = 0; rnd < 2; ++rnd) {
        const int rowg0 = rowBase + wr * 64 + rnd * 32;
#pragma unroll
        for (int ii = 0; ii < 2; ++ii)
#pragma unroll
            for (int j = 0; j < 4; ++j)
#pragma unroll
                for (int r2 = 0; r2 < 4; ++r2)
                    stg[(ii * 16 + lg * 4 + r2) * 64 + j * 16 + lr] = acc[rnd * 2 + ii][j][r2];

#pragma unroll
        for (int t = 0; t < 8; ++t) {
            const int idx = t * 256 + lane * 4;
            const int r = idx >> 6, c = idx & 63;
            const float4 v = *reinterpret_cast<const float4*>(&stg[idx]);
            ushort4 h;
            h.x = f16_of(v.x); h.y = f16_of(v.y);
            h.z = f16_of(v.z); h.w = f16_of(v.w);
            *reinterpret_cast<ushort4*>(
                &Ch[(long long)(rowg0 + r) * ldc + colg0 + c]) = h;
        }
    }
}

// ======== TERMS-1 GEMM: 256x256, BK=64, 2-barrier loop, 16x16x32 MFMA =======
__device__ inline void stage_ktile1(
    const unsigned short* __restrict__ Ah0, int lda,
    const unsigned short* __restrict__ Bh0, int ldb,
    int k0, unsigned short* buf, int w, int lane)
{
#pragma unroll
    for (int c = 0; c < 4; ++c) {
        const int r = c * 64 + w * 8 + (lane >> 3);
        const int co = ((lane & 7) ^ (r & 7)) * 8;
        const int lb = (c * 64 + w * 8) * 64;
        gload16(Ah0 + (long long)r * lda + k0 + co, buf + lb);
        gload16(Bh0 + (long long)r * ldb + k0 + co, buf + 16384 + lb);
    }
}

// OMODE: 0 = f32 C (+ optional NEG_INF*mask[col]);
//        4 = fused GV: cols<1024 -> plain f16 G (Ch, ldc); cols>=1024 -> f16
//            V^T store Ch2[b2][col-1024][s]  (rows are [B*S], b2=row>>11).
template <int OMODE>
__global__ __launch_bounds__(512, 2) void mfma_gemm1(
    const unsigned short* __restrict__ Ah_g, long long strideA, int lda,
    const unsigned short* __restrict__ Bh_g, long long strideB, int ldb,
    float* __restrict__ Cf, unsigned short* __restrict__ Ch, unsigned short* __restrict__ Ch2,
    long long strideC, int ldc, int K,
    const int* __restrict__ mask, long long strideMask)
{
    const int b = blockIdx.z;
    const int tid = threadIdx.x;
    const int w = tid >> 6, lane = tid & 63;
    const int wr = w >> 2, wc = w & 3;
    const int lr = lane & 15, lg = lane >> 4;
    const int rowBase = blockIdx.x * 256;
    const int colBase = blockIdx.y * 256;

    __shared__ unsigned short smem[65536];  // 128 KB: 2 x 64KB

    const unsigned short* Ah0 = Ah_g + (long long)b * strideA + (long long)rowBase * lda;
    const unsigned short* Bh0 = Bh_g + (long long)b * strideB + (long long)colBase * ldb;

    f32x4 acc[8][4] = {};
    const int NT = K / 64;

    stage_ktile1(Ah0, lda, Bh0, ldb, 0, smem, w, lane);
    __syncthreads();

    for (int kt = 0; kt < NT; ++kt) {
        const unsigned short* cbuf = smem + (kt & 1) * 32768;
        if (kt + 1 < NT)
            stage_ktile1(Ah0, lda, Bh0, ldb, (kt + 1) * 64,
                         smem + ((kt + 1) & 1) * 32768, w, lane);

        const unsigned short* tA = cbuf;
        const unsigned short* tB = cbuf + 16384;
        f16x8 bh[8];
#pragma unroll
        for (int j = 0; j < 4; ++j)
#pragma unroll
            for (int ks = 0; ks < 2; ++ks)
                bh[j * 2 + ks] = frag64(tB, wc * 64 + j * 16 + lr, ks * 4 + lg);
#pragma unroll
        for (int ih = 0; ih < 2; ++ih) {
            f16x8 ah[8];
#pragma unroll
            for (int f = 0; f < 4; ++f)
#pragma unroll
                for (int ks = 0; ks < 2; ++ks)
                    ah[f * 2 + ks] = frag64(tA, wr * 128 + ih * 64 + f * 16 + lr, ks * 4 + lg);
#pragma unroll
            for (int f = 0; f < 4; ++f)
#pragma unroll
                for (int j = 0; j < 4; ++j) {
                    f32x4 a = acc[ih * 4 + f][j];
                    a = __builtin_amdgcn_mfma_f32_16x16x32_f16(ah[f * 2 + 0], bh[j * 2 + 0], a, 0, 0, 0);
                    a = __builtin_amdgcn_mfma_f32_16x16x32_f16(ah[f * 2 + 1], bh[j * 2 + 1], a, 0, 0, 0);
                    acc[ih * 4 + f][j] = a;
                }
        }
        __syncthreads();
    }

    __syncthreads();
    float* stg = reinterpret_cast<float*>(smem) + w * 2048;
    const int colg0 = colBase + wc * 64;
#pragma unroll
    for (int rnd = 0; rnd < 4; ++rnd) {
        const int rowg0 = rowBase + wr * 128 + rnd * 32;
#pragma unroll
        for (int ii = 0; ii < 2; ++ii)
#pragma unroll
            for (int j = 0; j < 4; ++j)
#pragma unroll
                for (int r2 = 0; r2 < 4; ++r2)
                    stg[(ii * 16 + lg * 4 + r2) * 64 + j * 16 + lr] = acc[rnd * 2 + ii][j][r2];

        if constexpr (OMODE == 0) {
#pragma unroll
            for (int t = 0; t < 8; ++t) {
                const int idx = t * 256 + lane * 4;
                const int r = idx >> 6, c = idx & 63;
                float4 v = *reinterpret_cast<const float4*>(&stg[idx]);
                const int colg = colg0 + c;
                if (mask != nullptr) {
                    const int4 mv = *reinterpret_cast<const int4*>(
                        &mask[(long long)b * strideMask + colg]);
                    v.x += NEG_INF_F * (float)mv.x;
                    v.y += NEG_INF_F * (float)mv.y;
                    v.z += NEG_INF_F * (float)mv.z;
                    v.w += NEG_INF_F * (float)mv.w;
                }
                *reinterpret_cast<float4*>(
                    &Cf[(long long)b * strideC + (long long)(rowg0 + r) * ldc + colg]) = v;
            }
        } else {  // OMODE == 4: fused G | V^T
            if (colBase < 1024) {
#pragma unroll
                for (int t = 0; t < 8; ++t) {
                    const int idx = t * 256 + lane * 4;
                    const int r = idx >> 6, c = idx & 63;
                    const float4 v = *reinterpret_cast<const float4*>(&stg[idx]);
                    ushort4 h;
                    h.x = f16_of(v.x); h.y = f16_of(v.y);
                    h.z = f16_of(v.z); h.w = f16_of(v.w);
                    *reinterpret_cast<ushort4*>(
                        &Ch[(long long)(rowg0 + r) * ldc + colg0 + c]) = h;
                }
            } else {
                const int b2 = rowg0 >> 11;
                const int s0 = rowg0 & 2047;
                const int vcol = colg0 - 1024 + lane;
                alignas(16) unsigned short u[32];
#pragma unroll
                for (int rr = 0; rr < 32; ++rr) u[rr] = f16_of(stg[rr * 64 + lane]);
                unsigned short* vp = Ch2 + (long long)b2 * (1024LL * 2048)
                                   + (long long)vcol * 2048 + s0;
#pragma unroll
                for (int q = 0; q < 4; ++q)
                    *reinterpret_cast<uint4*>(vp + q * 8) =
                        *reinterpret_cast<const uint4*>(&u[q * 8]);
            }
        }
        __syncthreads();
    }
}

// ---------------- fused prep: weights + x conversion in one launch ----------
// z==0: wq tsplit; z==1: wk tsplit; z==2: wv cvt; z>=3: x cvt chunk (z-3)/16.
// tsplit: f32 [N][N] -> TRANSPOSED hi/lo f16: hi[j][i] = split(in[i][j]).
__global__ __launch_bounds__(256) void prep_kernel(
    const float* __restrict__ wq, const float* __restrict__ wk,
    const float* __restrict__ wv, const float* __restrict__ x,
    unsigned short* __restrict__ wqTh, unsigned short* __restrict__ wqTl,
    unsigned short* __restrict__ wkTh, unsigned short* __restrict__ wkTl,
    unsigned short* __restrict__ wvh, unsigned short* __restrict__ xh, int N)
{
    const int z = blockIdx.z;
    const int t = threadIdx.x;

    if (z >= 3) {
        // x cvt: chunk (z-3) of 16; 256 blocks/chunk; 4096 elems/block; 16/thread
        const long long base = ((long long)(z - 3) * 256 + blockIdx.x * 16 + blockIdx.y) * 4096
                             + (long long)t * 16;
#pragma unroll
        for (int q = 0; q < 4; ++q) {
            float4 v = *reinterpret_cast<const float4*>(&x[base + q * 4]);
            ushort4 h;
            h.x = f16_of(v.x); h.y = f16_of(v.y);
            h.z = f16_of(v.z); h.w = f16_of(v.w);
            *reinterpret_cast<ushort4*>(&xh[base + q * 4]) = h;
        }
        return;
    }

    const int bi = blockIdx.x * 64;
    const int bj = blockIdx.y * 64;

    if (z == 2) {
        const int r = t >> 4;
        const int c4 = (t & 15) * 4;
#pragma unroll
        for (int rr = 0; rr < 4; ++rr) {
            const int row = bi + rr * 16 + r;
            float4 v = *reinterpret_cast<const float4*>(&wv[(long long)row * N + bj + c4]);
            ushort4 h;
            h.x = f16_of(v.x); h.y = f16_of(v.y);
            h.z = f16_of(v.z); h.w = f16_of(v.w);
            *reinterpret_cast<ushort4*>(&wvh[(long long)row * N + bj + c4]) = h;
        }
        return;
    }

    const float* in = (z == 0) ? wq : wk;
    unsigned short* hi = (z == 0) ? wqTh : wkTh;
    unsigned short* lo = (z == 0) ? wqTl : wkTl;

    __shared__ float tile[64][65];
    const int c4 = (t & 15) * 4;
    const int r0 = (t >> 4) * 4;
#pragma unroll
    for (int rr = 0; rr < 4; ++rr) {
        float4 v = *reinterpret_cast<const float4*>(
            &in[(long long)(bi + r0 + rr) * N + bj + c4]);
        tile[r0 + rr][c4 + 0] = v.x;
        tile[r0 + rr][c4 + 1] = v.y;
        tile[r0 + rr][c4 + 2] = v.z;
        tile[r0 + rr][c4 + 3] = v.w;
    }
    __syncthreads();
    const int oc  = t >> 2;
    const int or0 = (t & 3) * 16;
    alignas(16) unsigned short uh[16], ul[16];
#pragma unroll
    for (int e = 0; e < 16; ++e) {
        const float f = tile[or0 + e][oc];
        const unsigned short h = f16_of(f);
        uh[e] = h;
        ul[e] = f16_of(f - f32_of(h));
    }
    unsigned short* hp = hi + (long long)(bj + oc) * N + bi + or0;
    unsigned short* lp = lo + (long long)(bj + oc) * N + bi + or0;
    *reinterpret_cast<uint4*>(hp)     = *reinterpret_cast<const uint4*>(&uh[0]);
    *reinterpret_cast<uint4*>(hp + 8) = *reinterpret_cast<const uint4*>(&uh[8]);
    *reinterpret_cast<uint4*>(lp)     = *reinterpret_cast<const uint4*>(&ul[0]);
    *reinterpret_cast<uint4*>(lp + 8) = *reinterpret_cast<const uint4*>(&ul[8]);
}

// In-place f32 row softmax (rows=16384, cols=2048) + f16 copy for PV.
__global__ __launch_bounds__(256) void softmax_kernel(
    float* __restrict__ s, unsigned short* __restrict__ p)
{
    const long long row = blockIdx.x;
    float* sp = s + row * 2048;
    const int tid = threadIdx.x;

    float v[8];
    *reinterpret_cast<float4*>(&v[0]) = *reinterpret_cast<const float4*>(&sp[tid * 8]);
    *reinterpret_cast<float4*>(&v[4]) = *reinterpret_cast<const float4*>(&sp[tid * 8 + 4]);

    float m = v[0];
#pragma unroll
    for (int i = 1; i < 8; ++i) m = fmaxf(m, v[i]);
#pragma unroll
    for (int off = 1; off < 64; off <<= 1) m = fmaxf(m, __shfl_xor(m, off));

    __shared__ float redm[4];
    __shared__ float reds[4];
    if ((tid & 63) == 0) redm[tid >> 6] = m;
    __syncthreads();
    m = fmaxf(fmaxf(redm[0], redm[1]), fmaxf(redm[2], redm[3]));

    float sum = 0.f;
#pragma unroll
    for (int i = 0; i < 8; ++i) {
        v[i] = __expf(v[i] - m);
        sum += v[i];
    }
#pragma unroll
    for (int off = 1; off < 64; off <<= 1) sum += __shfl_xor(sum, off);
    if ((tid & 63) == 0) reds[tid >> 6] = sum;
    __syncthreads();
    sum = reds[0] + reds[1] + reds[2] + reds[3];

    const float inv = 1.0f / sum;
#pragma unroll
    for (int i = 0; i < 8; ++i) v[i] *= inv;

    *reinterpret_cast<float4*>(&sp[tid * 8])     = *reinterpret_cast<const float4*>(&v[0]);
    *reinterpret_cast<float4*>(&sp[tid * 8 + 4]) = *reinterpret_cast<const float4*>(&v[4]);

    ushort4 o0, o1;
    o0.x = f16_of(v[0]); o0.y = f16_of(v[1]); o0.z = f16_of(v[2]); o0.w = f16_of(v[3]);
    o1.x = f16_of(v[4]); o1.y = f16_of(v[5]); o1.z = f16_of(v[6]); o1.w = f16_of(v[7]);
    *reinterpret_cast<ushort4*>(&p[row * 2048 + tid * 8])     = o0;
    *reinterpret_cast<ushort4*>(&p[row * 2048 + tid * 8 + 4]) = o1;
}

extern "C" void kernel_launch(void* const* d_in, const int* in_sizes, int n_in,
                              void* d_out, int out_size, void* d_ws, size_t ws_size,
                              hipStream_t stream)
{
    (void)in_sizes; (void)n_in; (void)out_size; (void)ws_size;

    const int S = 2048, D = 1024;
    const long long BS  = 8LL * S;          // 16384
    const long long SD  = (long long)S * D;
    const long long SS  = (long long)S * S;
    const long long BSD = BS * D;
    const long long DD  = (long long)D * D;

    const float* x    = (const float*)d_in[0];
    const int*   mask = (const int*)d_in[1];
    const float* wq   = (const float*)d_in[2];
    const float* wk   = (const float*)d_in[3];
    const float* wv   = (const float*)d_in[4];

    float* out = (float*)d_out;             // [BS, D] f32 (final)
    float* s   = out + BSD;                 // [B, S, S] f32 (final)

    // ws layout (halves):
    //   G [16384][1024] | (free BSD)        <- later p [B][S][S] = 2*BSD halves
    //   Vt [B][D][S] | MtWv [2048][1024] (Mt rows 0-1023, wv rows 1024-2047)
    unsigned short* G    = (unsigned short*)d_ws;
    unsigned short* p    = G;               // overwrites G + free
    unsigned short* Vt   = G + 2 * BSD;
    unsigned short* MtWv = G + 3 * BSD;
    unsigned short* Mth  = MtWv;
    unsigned short* wvh  = MtWv + DD;

    // xh lives in d_out's out-region until PV overwrites it
    unsigned short* xh = (unsigned short*)out;
    // transposed weight splits live in d_out's s-region until scores overwrites it
    unsigned short* wqTh = (unsigned short*)s;   // [1024][1024] = wq^T hi
    unsigned short* wqTl = wqTh + DD;
    unsigned short* wkTh = wqTl + DD;
    unsigned short* wkTl = wkTh + DD;

    dim3 blk256(256), blk512(512);

    // fused prep: wq/wk transposed splits, wv cvt, x cvt (one launch)
    prep_kernel<<<dim3(16, 16, 19), blk256, 0, stream>>>(
        wq, wk, wv, x, wqTh, wqTl, wkTh, wkTl, wvh, xh, D);

    // Mt[j][i] = sum_e wk[e][j]*wq[e][i]; A = (wkTh,wkTl) split, B = wqTh, f16 out
    gemm2<<<dim3(8, 4, 1), blk512, 0, stream>>>(
        wkTh, wkTl, D, wqTh, D, Mth, D, D);

    // Fused [G | V^T] = xh @ [Mt | wv]^T  (1-term, N=2048, mixed epilogue)
    mfma_gemm1<4><<<dim3(64, 8, 1), blk512, 0, stream>>>(
        xh, 0, D, MtWv, 0, D,
        nullptr, G, Vt, 0, D, D, nullptr, 0);

    // scores = G @ xh^T + NEG_INF*mask  (1-term, f32 out)
    mfma_gemm1<0><<<dim3(8, 8, 8), blk512, 0, stream>>>(
        G, SD, D, xh, SD, D,
        s, nullptr, nullptr, SS, S, D, mask, S);

    // softmax in place + f16 p for PV (p overwrites G)
    softmax_kernel<<<dim3(16384), blk256, 0, stream>>>(s, p);

    // out = p @ V = p @ (V^T)^T  (f32 out)
    mfma_gemm1<0><<<dim3(8, 4, 8), blk512, 0, stream>>>(
        p, SS, S, Vt, SD, S, out, nullptr, nullptr, SD, D, S, nullptr, 0);
}